// Round 18
// baseline (609.422 us; speedup 1.0000x reference)
//
#include <hip/hip_runtime.h>

typedef unsigned int u32;
typedef unsigned short u16;
typedef __attribute__((ext_vector_type(8))) short bf16x8;
typedef __attribute__((ext_vector_type(4))) float f32x4;

#define DEVI static __device__ __forceinline__

DEVI u16 f2bf(float f) {
    u32 u = __float_as_uint(f);
    u32 r = u + 0x7FFFu + ((u >> 16) & 1u);   // RNE (inputs finite)
    return (u16)(r >> 16);
}
DEVI float bf2f(u16 s) { return __uint_as_float(((u32)s) << 16); }
DEVI void split2(float a, u16& h, u16& l) {   // a ≈ hi + lo, residual ≤ 2^-18|a|
    h = f2bf(a);
    l = f2bf(a - bf2f(h));
}
DEVI int swz(int row) { return (row & 3) ^ ((row >> 2) & 3); }  // 32-col-tile swizzle key

// direct global->LDS DMA, 16 B/lane; LDS dest = wave-uniform base + lane*16
DEVI void gload16(const void* g, void* l) {
    __builtin_amdgcn_global_load_lds(
        (const __attribute__((address_space(1))) u32*)g,
        (__attribute__((address_space(3))) u32*)l, 16, 0, 0);
}

union U4 { uint4 v; u16 s[8]; };

// ---------------------------------------------------------------- weight packing (split + permute, lane-linear)
__global__ __launch_bounds__(256) void pack_w1_kernel(const float* __restrict__ wsrc,
                                                      u16* __restrict__ ph, u16* __restrict__ pl) {
    int i = blockIdx.x * 256 + threadIdx.x;          // 16384 octets
    int s = i >> 10, rem = i & 1023;
    int rg = rem >> 6, l = rem & 63;
    int row = rg * 16 + (l >> 2);
    int col = s * 32 + (((l & 3) ^ ((l >> 2) & 3) ^ ((l >> 4) & 3)) * 8);
    U4 hh, ll;
#pragma unroll
    for (int e = 0; e < 8; ++e) split2(wsrc[(size_t)row * 512 + col + e], hh.s[e], ll.s[e]);
    *reinterpret_cast<uint4*>(&ph[(size_t)i * 8]) = hh.v;
    *reinterpret_cast<uint4*>(&pl[(size_t)i * 8]) = ll.v;
}
__global__ __launch_bounds__(256) void pack_w2_kernel(const float* __restrict__ wsrc,
                                                      u16* __restrict__ ph, u16* __restrict__ pl) {
    int i = blockIdx.x * 256 + threadIdx.x;          // 8192 octets
    int w_ = i >> 11, s2 = (i >> 8) & 7, ni = (i >> 6) & 3, l = i & 63;
    int row = w_ * 64 + ni * 16 + (l & 15);
    int col = s2 * 32 + (l >> 4) * 8;
    U4 hh, ll;
#pragma unroll
    for (int e = 0; e < 8; ++e) split2(wsrc[(size_t)row * 256 + col + e], hh.s[e], ll.s[e]);
    *reinterpret_cast<uint4*>(&ph[(size_t)i * 8]) = hh.v;
    *reinterpret_cast<uint4*>(&pl[(size_t)i * 8]) = ll.v;
}
__global__ __launch_bounds__(256) void pack_wu_kernel(const float* __restrict__ wsrc,
                                                      u16* __restrict__ ph, u16* __restrict__ pl) {
    int i = blockIdx.x * 256 + threadIdx.x;          // 16384 octets
    int o4 = i >> 12, wc = (i >> 11) & 1, s = (i >> 8) & 7, ni = (i >> 6) & 3, l = i & 63;
    int row = o4 * 128 + wc * 64 + ni * 16 + (l & 15);
    int col = s * 32 + (l >> 4) * 8;
    U4 hh, ll;
#pragma unroll
    for (int e = 0; e < 8; ++e) split2(wsrc[(size_t)row * 256 + col + e], hh.s[e], ll.s[e]);
    *reinterpret_cast<uint4*>(&ph[(size_t)i * 8]) = hh.v;
    *reinterpret_cast<uint4*>(&pl[(size_t)i * 8]) = ll.v;
}

// ---------------------------------------------------------------- proxy-side K/V (tiny, fp32 VALU)
struct KVArgs {
    const float *proxy;
    const float *ow1, *og1, *ob1, *om1, *ov1;
    const float *ow2, *og2, *ob2, *om2, *ov2;
    const float *dw,  *dg,  *db,  *dm,  *dv;
    float *kmat;   // [B][256][19]
    float *vmat;   // [B][19][256]
};
__global__ __launch_bounds__(256) void kv_kernel(KVArgs a) {
    __shared__ float pl[512 * 19];
    __shared__ float t1[256 * 19];
    const int t = threadIdx.x;
    const int b = blockIdx.x;
    const float* pb = a.proxy + (size_t)b * 512 * 19;
    for (int i = t; i < 512 * 19; i += 256) pl[i] = pb[i];
    __syncthreads();
    const int o = t;
    {
        float acc[19] = {0.f};
        const float* wr = a.ow1 + (size_t)o * 512;
        for (int c = 0; c < 512; ++c) {
            float wv = wr[c];
#pragma unroll
            for (int kk = 0; kk < 19; ++kk) acc[kk] += wv * pl[c * 19 + kk];
        }
        float sc = a.og1[o] * __frsqrt_rn(a.ov1[o] + 1e-5f);
        float sh = a.ob1[o] - a.om1[o] * sc;
#pragma unroll
        for (int kk = 0; kk < 19; ++kk) t1[o * 19 + kk] = fmaxf(acc[kk] * sc + sh, 0.f);
    }
    __syncthreads();
    {
        float acc[19] = {0.f};
        const float* wr = a.ow2 + (size_t)o * 256;
        for (int c = 0; c < 256; ++c) {
            float wv = wr[c];
#pragma unroll
            for (int kk = 0; kk < 19; ++kk) acc[kk] += wv * t1[c * 19 + kk];
        }
        float sc = a.og2[o] * __frsqrt_rn(a.ov2[o] + 1e-5f);
        float sh = a.ob2[o] - a.om2[o] * sc;
#pragma unroll
        for (int kk = 0; kk < 19; ++kk)
            a.kmat[((size_t)b * 256 + o) * 19 + kk] = fmaxf(acc[kk] * sc + sh, 0.f);
    }
    {
        float acc[19] = {0.f};
        const float* wr = a.dw + (size_t)o * 512;
        for (int c = 0; c < 512; ++c) {
            float wv = wr[c];
#pragma unroll
            for (int kk = 0; kk < 19; ++kk) acc[kk] += wv * pl[c * 19 + kk];
        }
        float sc = a.dg[o] * __frsqrt_rn(a.dv[o] + 1e-5f);
        float sh = a.db[o] - a.dm[o] * sc;
#pragma unroll
        for (int kk = 0; kk < 19; ++kk)
            a.vmat[((size_t)b * 19 + kk) * 256 + o] = fmaxf(acc[kk] * sc + sh, 0.f);
    }
}

// ---------------------------------------------------------------- attention: 16 px/block, q2 LDS-staged coalesced
// 16 threads/px (cg = t>>4 handles 16 ch). qs stride 261 (gcd(5,32)=1 -> conflict-free).
// Reduction: shfl_xor(16,32) folds in-wave cg, sp[4][16][19] folds waves.
// ctx stored in gemm_up A-fragment order (R17-proven mapping).
struct AttnArgs { const float* q2f; const float* kmat; const float* vmat;
                  u16* ctxh; u16* ctxl; long long p_off; };
__global__ __launch_bounds__(256, 2) void attn_kernel(AttnArgs a) {
    __shared__ float qs[16 * 261];    // 16704 B
    __shared__ float kl[4864];        // [c][19]
    __shared__ float vl[4864];        // [kk][256]
    __shared__ float sp[4 * 16 * 19]; // wave partials
    const int t = threadIdx.x;
    const int px = t & 15, cg = t >> 4;                // cg 0..15
    const int w = t >> 6, l = t & 63;
    const size_t pl_ = (size_t)blockIdx.x * 16;        // pass-local pixel base
    const size_t gpx0 = (size_t)a.p_off + pl_;         // global pixel base (mult of 16)
    const int b = (int)(gpx0 >> 14);
    for (int i = t; i < 4864; i += 256) { kl[i] = a.kmat[(size_t)b * 4864 + i];
                                          vl[i] = a.vmat[(size_t)b * 4864 + i]; }
    // stage q2 tile coalescedly: 4096 floats = 1024 float4
    {
        const float* src = a.q2f + pl_ * 256;
#pragma unroll
        for (int j = 0; j < 4; ++j) {
            int f = j * 256 + t;                       // float4 index
            float4 v = reinterpret_cast<const float4*>(src)[f];
            int pr = f >> 6, col = (f & 63) * 4;
            *reinterpret_cast<float4*>(&qs[pr * 261 + col]) = v;
        }
    }
    __syncthreads();
    // partial sims over this thread's 16 channels
    float sim[19];
#pragma unroll
    for (int kk = 0; kk < 19; ++kk) sim[kk] = 0.f;
#pragma unroll 4
    for (int i = 0; i < 16; ++i) {
        int c = cg * 16 + i;
        float qv = qs[px * 261 + c];
#pragma unroll
        for (int kk = 0; kk < 19; ++kk) sim[kk] += qv * kl[c * 19 + kk];
    }
    // fold in-wave (lanes px, px^16, px^32, px^48 share px)
#pragma unroll
    for (int kk = 0; kk < 19; ++kk) {
        sim[kk] += __shfl_xor(sim[kk], 16);
        sim[kk] += __shfl_xor(sim[kk], 32);
    }
    if ((l >> 4) == 0) {
#pragma unroll
        for (int kk = 0; kk < 19; ++kk) sp[w * 304 + px * 19 + kk] = sim[kk];
    }
    __syncthreads();
    // combine waves + softmax (redundant per thread; sp reads broadcast within px-group)
    float wgt[19];
    float mx = -1e30f;
#pragma unroll
    for (int kk = 0; kk < 19; ++kk) {
        float s0 = sp[px * 19 + kk] + sp[304 + px * 19 + kk]
                 + sp[608 + px * 19 + kk] + sp[912 + px * 19 + kk];
        wgt[kk] = s0 * 0.0625f;
        mx = fmaxf(mx, wgt[kk]);
    }
    float ssum = 0.f;
#pragma unroll
    for (int kk = 0; kk < 19; ++kk) { wgt[kk] = __expf(wgt[kk] - mx); ssum += wgt[kk]; }
    const float inv = 1.f / ssum;
#pragma unroll
    for (int kk = 0; kk < 19; ++kk) wgt[kk] *= inv;
    // ctx for this thread's 16 channels -> fragment-order stores
    const int Pg = (int)gpx0 + px;
    const int tile = Pg >> 6;
    const int pgg = (Pg >> 4) & 3;
    u16* th = a.ctxh + (size_t)tile * 16384;
    u16* tl = a.ctxl + (size_t)tile * 16384;
#pragma unroll
    for (int jj = 0; jj < 2; ++jj) {
        const int j = cg * 2 + jj;                     // channel octet
        const int s = j >> 2, l4c = j & 3;
        U4 hh, ll;
#pragma unroll
        for (int e = 0; e < 8; ++e) {
            int c = j * 8 + e;
            float acc = 0.f;
#pragma unroll
            for (int kk = 0; kk < 19; ++kk) acc += wgt[kk] * vl[kk * 256 + c];
            split2(acc, hh.s[e], ll.s[e]);
        }
        const int off = (s * 4 + pgg) * 512 + (l4c * 16 + px) * 8;
        *reinterpret_cast<uint4*>(&th[off]) = hh.v;
        *reinterpret_cast<uint4*>(&tl[off]) = ll.v;
    }
}

// ---------------------------------------------------------------- FUSED gemm1+gemm2, 128-px blocks, 2 blocks/CU
// Phase 1: acc1[4][8] (wb reads amortized over 2x MFMA -> LDS pipe balanced);
//   xs SINGLE buffer (16 KB) + wb dbuf (64 KB) = 80 KB; 2 barriers/step.
// Phase 2: chunk-PAIRS (32 px q1, all 4 waves write), W2 packed direct-from-global.
struct F12Args {
    const float* Xf;
    const u16 *W1h, *W1l, *W2h, *W2l;   // packed
    const float *g1, *b1, *m1, *v1;
    const float *g2, *b2, *m2, *v2;
    float* q2f;     // [chunk_px][256] fp32
    int m_off;
};
__global__ __launch_bounds__(256, 2) void fused12_kernel(F12Args a) {
    __shared__ char LB[81920];
    u16* xs = (u16*)LB;               // phase1: 2 planes x [128][32] u16 (16384 B, single buf)
    u16* wb = (u16*)(LB + 16384);     // phase1: 2 buf x 2 planes x [256][32] u16 (65536 B)
    u16* q1 = (u16*)LB;               // phase2: 2 planes x [32][280] u16 (35840 B)
    float* tf = (float*)LB;           // phase2 epilogue: [32][260] f32 (33280 B), aliases q1

    const int t = threadIdx.x;
    const int l = t & 63, w = t >> 6;
    const int wr = w >> 1, wc = w & 1;
    const int l15 = l & 15, l4 = l >> 4;
    const int mloc = blockIdx.x * 128;
    const int mg = a.m_off + mloc;
    const int bb = mg >> 14, nb = mg & 16383;   // 128 | 16384 -> no batch straddle

    f32x4 acc1[4][8];
#pragma unroll
    for (int mi = 0; mi < 4; ++mi)
#pragma unroll
        for (int ni = 0; ni < 8; ++ni) acc1[mi][ni] = f32x4{0.f, 0.f, 0.f, 0.f};

    float fxA[8], fxB[8];             // two tasks: px = t&127, octs {t>>7, 2+(t>>7)}

    auto loadX = [&](int s) {
        const int px = t & 127, oa = t >> 7;
        const float* s0 = a.Xf + (((size_t)bb * 512 + s * 32 + oa * 8) << 14) + nb + px;
        const float* s1 = a.Xf + (((size_t)bb * 512 + s * 32 + (oa + 2) * 8) << 14) + nb + px;
#pragma unroll
        for (int e = 0; e < 8; ++e) { fxA[e] = s0[(size_t)e << 14]; fxB[e] = s1[(size_t)e << 14]; }
    };
    auto writeX = [&]() {
        const int px = t & 127, oa = t >> 7;
        U4 phA, plA, phB, plB;
#pragma unroll
        for (int e = 0; e < 8; ++e) { split2(fxA[e], phA.s[e], plA.s[e]);
                                      split2(fxB[e], phB.s[e], plB.s[e]); }
        int posA = px * 32 + ((oa ^ swz(px)) * 8);
        int posB = px * 32 + (((oa + 2) ^ swz(px)) * 8);
        *reinterpret_cast<uint4*>(&xs[posA]) = phA.v;
        *reinterpret_cast<uint4*>(&xs[4096 + posA]) = plA.v;
        *reinterpret_cast<uint4*>(&xs[posB]) = phB.v;
        *reinterpret_cast<uint4*>(&xs[4096 + posB]) = plB.v;
    };
    auto dmaW1 = [&](int s, int buf) {
        const u16* bh = a.W1h + (size_t)s * 8192 + l * 8;
        const u16* bl2 = a.W1l + (size_t)s * 8192 + l * 8;
#pragma unroll
        for (int g = 0; g < 4; ++g) {
            const int rg = w * 4 + g;
            gload16(bh + rg * 512, &wb[buf * 16384 + rg * 512]);
            gload16(bl2 + rg * 512, &wb[buf * 16384 + 8192 + rg * 512]);
        }
    };

    // ---------------- phase 1: K=512 in 16 steps of 32
    loadX(0); dmaW1(0, 0);
    writeX();
    __syncthreads();                             // xs(0) + wb(0) ready
    int cur = 0;
    for (int s = 0; s < 16; ++s) {
        if (s < 15) dmaW1(s + 1, cur ^ 1);       // covered by MFMA below
        bf16x8 ah[4], am[4];
#pragma unroll
        for (int mi = 0; mi < 4; ++mi) {
            int ar = wr * 64 + mi * 16 + l15;
            int ap = ar * 32 + ((l4 ^ swz(ar)) * 8);
            ah[mi] = *reinterpret_cast<const bf16x8*>(&xs[ap]);
            am[mi] = *reinterpret_cast<const bf16x8*>(&xs[4096 + ap]);
        }
#pragma unroll
        for (int ni = 0; ni < 8; ++ni) {
            int br = wc * 128 + ni * 16 + l15;
            int bp = cur * 16384 + br * 32 + ((l4 ^ swz(br)) * 8);
            bf16x8 bh = *reinterpret_cast<const bf16x8*>(&wb[bp]);
            bf16x8 bl_ = *reinterpret_cast<const bf16x8*>(&wb[8192 + bp]);
#pragma unroll
            for (int mi = 0; mi < 4; ++mi) {
                acc1[mi][ni] = __builtin_amdgcn_mfma_f32_16x16x32_bf16(ah[mi], bh, acc1[mi][ni], 0, 0, 0);
                acc1[mi][ni] = __builtin_amdgcn_mfma_f32_16x16x32_bf16(ah[mi], bl_, acc1[mi][ni], 0, 0, 0);
                acc1[mi][ni] = __builtin_amdgcn_mfma_f32_16x16x32_bf16(am[mi], bh, acc1[mi][ni], 0, 0, 0);
            }
        }
        __syncthreads();                         // barA: xs reads done, dma(s+1) drained
        if (s < 15) {
            loadX(s + 1);                        // issue x loads (other block covers window)
            writeX();                            // overwrite single xs
            __syncthreads();                     // barB: xs(s+1) visible
        }
        cur ^= 1;
    }

    // BN coefficients
    float scl1[8], shf1[8];
#pragma unroll
    for (int ni = 0; ni < 8; ++ni) {
        int o = wc * 128 + ni * 16 + l15;
        scl1[ni] = a.g1[o] * __frsqrt_rn(a.v1[o] + 1e-5f);
        shf1[ni] = a.b1[o] - a.m1[o] * scl1[ni];
    }
    float scl2[4], shf2[4];
#pragma unroll
    for (int ni = 0; ni < 4; ++ni) {
        int o = w * 64 + ni * 16 + l15;
        scl2[ni] = a.g2[o] * __frsqrt_rn(a.v2[o] + 1e-5f);
        shf2[ni] = a.b2[o] - a.m2[o] * scl2[ni];
    }

    // ---------------- phase 2: 4 chunk-pairs of 32 px (cp: wr0 -> rows 0-15, wr1 -> rows 16-31)
#pragma unroll
    for (int cp = 0; cp < 4; ++cp) {
        __syncthreads();                       // prior LDS users done
        // ALL waves write their quarter: wave (wr,wc) -> rows wr*16+px_l, cols wc*128+...
#pragma unroll
        for (int ni = 0; ni < 8; ++ni) {
            int o1 = wc * 128 + ni * 16 + l15;
#pragma unroll
            for (int r = 0; r < 4; ++r) {
                int row = wr * 16 + l4 * 4 + r;
                float y = fmaxf(acc1[cp][ni][r] * scl1[ni] + shf1[ni], 0.f);
                u16 h, lo; split2(y, h, lo);
                int pos = row * 280 + o1;
                q1[pos] = h;
                q1[8960 + pos] = lo;
            }
        }
        __syncthreads();                       // q1 visible

        f32x4 acc2[2][4];
#pragma unroll
        for (int m = 0; m < 2; ++m)
#pragma unroll
            for (int ni = 0; ni < 4; ++ni) acc2[m][ni] = f32x4{0.f, 0.f, 0.f, 0.f};

#pragma unroll
        for (int s2 = 0; s2 < 8; ++s2) {       // barrier-free; W2 packed 1 KB loads
            bf16x8 a2h[2], a2m[2];
#pragma unroll
            for (int m = 0; m < 2; ++m) {
                int ap = (m * 16 + l15) * 280 + (s2 * 4 + l4) * 8;
                a2h[m] = *reinterpret_cast<const bf16x8*>(&q1[ap]);
                a2m[m] = *reinterpret_cast<const bf16x8*>(&q1[8960 + ap]);
            }
            const size_t bo0 = (size_t)(w * 8 + s2) * 2048 + l * 8;
#pragma unroll
            for (int ni = 0; ni < 4; ++ni) {
                bf16x8 b2h = *reinterpret_cast<const bf16x8*>(&a.W2h[bo0 + ni * 512]);
                bf16x8 b2l = *reinterpret_cast<const bf16x8*>(&a.W2l[bo0 + ni * 512]);
#pragma unroll
                for (int m = 0; m < 2; ++m) {
                    acc2[m][ni] = __builtin_amdgcn_mfma_f32_16x16x32_bf16(a2h[m], b2h, acc2[m][ni], 0, 0, 0);
                    acc2[m][ni] = __builtin_amdgcn_mfma_f32_16x16x32_bf16(a2h[m], b2l, acc2[m][ni], 0, 0, 0);
                    acc2[m][ni] = __builtin_amdgcn_mfma_f32_16x16x32_bf16(a2m[m], b2h, acc2[m][ni], 0, 0, 0);
                }
            }
        }
        __syncthreads();                       // q1 reads done before tf overwrite (alias)

        // q2 epilogue: BN2+ReLU -> tf [32][260] -> coalesced float4 stores
#pragma unroll
        for (int m = 0; m < 2; ++m)
#pragma unroll
            for (int ni = 0; ni < 4; ++ni) {
                int o2 = w * 64 + ni * 16 + l15;
#pragma unroll
                for (int r = 0; r < 4; ++r) {
                    int row = m * 16 + l4 * 4 + r;
                    tf[row * 260 + o2] = fmaxf(acc2[m][ni][r] * scl2[ni] + shf2[ni], 0.f);
                }
            }
        __syncthreads();
#pragma unroll
        for (int j = 0; j < 8; ++j) {          // 32 rows x 64 float4
            int task = j * 256 + t;
            int row = task >> 6, c4 = task & 63;
            int gpx = mloc + (row >> 4) * 64 + cp * 16 + (row & 15);
            *reinterpret_cast<float4*>(&a.q2f[(size_t)gpx * 256 + c4 * 4]) =
                *reinterpret_cast<const float4*>(&tf[row * 260 + c4 * 4]);
        }
    }
}

// ---------------------------------------------------------------- gemm_up: packed ctx + packed uw -> out (unchanged R17)
struct GUArgs {
    const u16 *Ah, *Al, *Wh, *Wl;     // packed
    const float *gg, *bbv, *mmv, *vvv;
    float* Yf;
};
__global__ __launch_bounds__(256, 4) void gemm_up_kernel(GUArgs a) {
    __shared__ float ldsf[128 * 68];          // epilogue only (34816 B)
    const int t = threadIdx.x;
    const int l = t & 63;
    const int w = t >> 6;
    const int wr = w >> 1, wc = w & 1;
    const int l15 = l & 15, l4 = l >> 4;
    const int id = blockIdx.y * 4 + blockIdx.x;
    const int wid = (id & 7) * 1024 + (id >> 3);  // bijective XCD chunking (nwg=8192)
    const int o0 = (wid & 3) * 128;
    const int m  = (wid >> 2) * 64;
    const int bb = m >> 14;
    const int nb = m & 16383;

    f32x4 acc[2][4];
#pragma unroll
    for (int mi = 0; mi < 2; ++mi)
#pragma unroll
        for (int ni = 0; ni < 4; ++ni) acc[mi][ni] = f32x4{0.f, 0.f, 0.f, 0.f};

    const size_t aoff0 = (size_t)(wid >> 2) * 16384 + (size_t)(wr * 2) * 512 + l * 8;
    const size_t woff0 = (size_t)(((wid & 3) * 2 + wc) * 8) * 2048 + l * 8;

#pragma unroll 2
    for (int s = 0; s < 8; ++s) {             // barrier-free
        const size_t as = aoff0 + (size_t)s * 2048;
        const size_t wso = woff0 + (size_t)s * 2048;
        bf16x8 ah[2], al[2], bh[4], bl[4];
#pragma unroll
        for (int mi = 0; mi < 2; ++mi) {
            ah[mi] = *reinterpret_cast<const bf16x8*>(a.Ah + as + mi * 512);
            al[mi] = *reinterpret_cast<const bf16x8*>(a.Al + as + mi * 512);
        }
#pragma unroll
        for (int ni = 0; ni < 4; ++ni) {
            bh[ni] = *reinterpret_cast<const bf16x8*>(a.Wh + wso + ni * 512);
            bl[ni] = *reinterpret_cast<const bf16x8*>(a.Wl + wso + ni * 512);
        }
#pragma unroll
        for (int mi = 0; mi < 2; ++mi)
#pragma unroll
            for (int ni = 0; ni < 4; ++ni) {
                acc[mi][ni] = __builtin_amdgcn_mfma_f32_16x16x32_bf16(ah[mi], bh[ni], acc[mi][ni], 0, 0, 0);
                acc[mi][ni] = __builtin_amdgcn_mfma_f32_16x16x32_bf16(ah[mi], bl[ni], acc[mi][ni], 0, 0, 0);
                acc[mi][ni] = __builtin_amdgcn_mfma_f32_16x16x32_bf16(al[mi], bh[ni], acc[mi][ni], 0, 0, 0);
            }
    }

    float scl[4], shf[4];
#pragma unroll
    for (int ni = 0; ni < 4; ++ni) {
        int o = o0 + wc * 64 + ni * 16 + l15;
        scl[ni] = a.gg[o] * __frsqrt_rn(a.vvv[o] + 1e-5f);
        shf[ni] = a.bbv[o] - a.mmv[o] * scl[ni];
    }

#pragma unroll
    for (int ni = 0; ni < 4; ++ni) {
        int o_l = wc * 64 + ni * 16 + l15;
#pragma unroll
        for (int mi = 0; mi < 2; ++mi)
#pragma unroll
            for (int r = 0; r < 4; ++r) {
                int n_l = wr * 32 + mi * 16 + l4 * 4 + r;
                float y = fmaxf(acc[mi][ni][r] * scl[ni] + shf[ni], 0.f);
                ldsf[o_l * 68 + n_l] = y;
            }
    }
    __syncthreads();
#pragma unroll
    for (int j = 0; j < 8; ++j) {
        int idx = j * 256 + t;
        int row = idx >> 4, c4 = (idx & 15) * 4;
        *reinterpret_cast<float4*>(&a.Yf[((size_t)bb << 23) + (size_t)(o0 + row) * 16384 + nb + c4]) =
            *reinterpret_cast<const float4*>(&ldsf[row * 68 + c4]);
    }
}

// ---------------------------------------------------------------- launch
extern "C" void kernel_launch(void* const* d_in, const int* in_sizes, int n_in,
                              void* d_out, int out_size, void* d_ws, size_t ws_size,
                              hipStream_t stream) {
    const float* x     = (const float*)d_in[0];
    const float* proxy = (const float*)d_in[1];
    const float* pw1 = (const float*)d_in[2];
    const float* pg1 = (const float*)d_in[3];
    const float* pb1 = (const float*)d_in[4];
    const float* pm1 = (const float*)d_in[5];
    const float* pv1 = (const float*)d_in[6];
    const float* pw2 = (const float*)d_in[7];
    const float* pg2 = (const float*)d_in[8];
    const float* pb2 = (const float*)d_in[9];
    const float* pm2 = (const float*)d_in[10];
    const float* pv2 = (const float*)d_in[11];
    const float* ow1 = (const float*)d_in[12];
    const float* og1 = (const float*)d_in[13];
    const float* ob1 = (const float*)d_in[14];
    const float* om1 = (const float*)d_in[15];
    const float* ov1 = (const float*)d_in[16];
    const float* ow2 = (const float*)d_in[17];
    const float* og2 = (const float*)d_in[18];
    const float* ob2 = (const float*)d_in[19];
    const float* om2 = (const float*)d_in[20];
    const float* ov2 = (const float*)d_in[21];
    const float* dw  = (const float*)d_in[22];
    const float* dg  = (const float*)d_in[23];
    const float* db  = (const float*)d_in[24];
    const float* dm  = (const float*)d_in[25];
    const float* dv  = (const float*)d_in[26];
    const float* uw  = (const float*)d_in[27];
    const float* ug  = (const float*)d_in[28];
    const float* ub  = (const float*)d_in[29];
    const float* um  = (const float*)d_in[30];
    const float* uv  = (const float*)d_in[31];

    char* ws = (char*)d_ws;
    u16* w1ph = (u16*)(ws + 0);                  // 262144 B (packed)
    u16* w1pl = (u16*)(ws + 262144);
    u16* w2ph = (u16*)(ws + 524288);             // 131072 B (packed)
    u16* w2pl = (u16*)(ws + 655360);
    u16* wuph = (u16*)(ws + 786432);             // 262144 B (packed)
    u16* wupl = (u16*)(ws + 1048576);
    float* kmat = (float*)(ws + 1310720);        // 155648 B
    float* vmat = (float*)(ws + 1466368);        // 155648 B -> ends 1622016
    u16* ctxh = (u16*)(ws + 2097152);            // 67108864 B (fragment-order)
    u16* ctxl = (u16*)(ws + 69206016);           // 67108864 B -> ends 136314880
    float* q2f = (float*)(ws + 136314880ull);    // 134217728 B, [px][256] fp32

    pack_w1_kernel<<<64, 256, 0, stream>>>(pw1, w1ph, w1pl);
    pack_w2_kernel<<<32, 256, 0, stream>>>(pw2, w2ph, w2pl);
    pack_wu_kernel<<<64, 256, 0, stream>>>(uw,  wuph, wupl);

    KVArgs ka{proxy, ow1, og1, ob1, om1, ov1, ow2, og2, ob2, om2, ov2,
              dw, dg, db, dm, dv, kmat, vmat};
    kv_kernel<<<8, 256, 0, stream>>>(ka);

    // fused12: x -> q1 -> q2 (128-px blocks)
    F12Args fa{x, w1ph, w1pl, w2ph, w2pl,
               pg1, pb1, pm1, pv1, pg2, pb2, pm2, pv2, q2f, 0};
    fused12_kernel<<<1024, 256, 0, stream>>>(fa);

    // attention: 16 px/block, LDS-staged coalesced q reads
    AttnArgs aa{q2f, kmat, vmat, ctxh, ctxl, 0};
    attn_kernel<<<8192, 256, 0, stream>>>(aa);

    // gemm_up: packed ctx -> out[b][o][n] fp32
    GUArgs ga{ctxh, ctxl, wuph, wupl, ug, ub, um, uv, (float*)d_out};
    gemm_up_kernel<<<dim3(4, 2048), 256, 0, stream>>>(ga);
}

// Round 19
// 600.579 us; speedup vs baseline: 1.0147x; 1.0147x over previous
//
#include <hip/hip_runtime.h>

typedef unsigned int u32;
typedef unsigned short u16;
typedef __attribute__((ext_vector_type(8))) short bf16x8;
typedef __attribute__((ext_vector_type(4))) float f32x4;

#define DEVI static __device__ __forceinline__

DEVI u16 f2bf(float f) {
    u32 u = __float_as_uint(f);
    u32 r = u + 0x7FFFu + ((u >> 16) & 1u);   // RNE (inputs finite)
    return (u16)(r >> 16);
}
DEVI float bf2f(u16 s) { return __uint_as_float(((u32)s) << 16); }
DEVI void split2(float a, u16& h, u16& l) {   // a ≈ hi + lo, residual ≤ 2^-18|a|
    h = f2bf(a);
    l = f2bf(a - bf2f(h));
}
DEVI int swz(int row) { return (row & 3) ^ ((row >> 2) & 3); }  // 32-col-tile swizzle key

// direct global->LDS DMA, 16 B/lane; LDS dest = wave-uniform base + lane*16
DEVI void gload16(const void* g, void* l) {
    __builtin_amdgcn_global_load_lds(
        (const __attribute__((address_space(1))) u32*)g,
        (__attribute__((address_space(3))) u32*)l, 16, 0, 0);
}

union U4 { uint4 v; u16 s[8]; };

// ---------------------------------------------------------------- weight packing (split + permute, lane-linear)
__global__ __launch_bounds__(256) void pack_w1_kernel(const float* __restrict__ wsrc,
                                                      u16* __restrict__ ph, u16* __restrict__ pl) {
    int i = blockIdx.x * 256 + threadIdx.x;          // 16384 octets
    int s = i >> 10, rem = i & 1023;
    int rg = rem >> 6, l = rem & 63;
    int row = rg * 16 + (l >> 2);
    int col = s * 32 + (((l & 3) ^ ((l >> 2) & 3) ^ ((l >> 4) & 3)) * 8);
    U4 hh, ll;
#pragma unroll
    for (int e = 0; e < 8; ++e) split2(wsrc[(size_t)row * 512 + col + e], hh.s[e], ll.s[e]);
    *reinterpret_cast<uint4*>(&ph[(size_t)i * 8]) = hh.v;
    *reinterpret_cast<uint4*>(&pl[(size_t)i * 8]) = ll.v;
}
__global__ __launch_bounds__(256) void pack_w2_kernel(const float* __restrict__ wsrc,
                                                      u16* __restrict__ ph, u16* __restrict__ pl) {
    int i = blockIdx.x * 256 + threadIdx.x;          // 8192 octets
    int w_ = i >> 11, s2 = (i >> 8) & 7, ni = (i >> 6) & 3, l = i & 63;
    int row = w_ * 64 + ni * 16 + (l & 15);
    int col = s2 * 32 + (l >> 4) * 8;
    U4 hh, ll;
#pragma unroll
    for (int e = 0; e < 8; ++e) split2(wsrc[(size_t)row * 256 + col + e], hh.s[e], ll.s[e]);
    *reinterpret_cast<uint4*>(&ph[(size_t)i * 8]) = hh.v;
    *reinterpret_cast<uint4*>(&pl[(size_t)i * 8]) = ll.v;
}
__global__ __launch_bounds__(256) void pack_wu_kernel(const float* __restrict__ wsrc,
                                                      u16* __restrict__ ph, u16* __restrict__ pl) {
    int i = blockIdx.x * 256 + threadIdx.x;          // 16384 octets
    int o4 = i >> 12, wc = (i >> 11) & 1, s = (i >> 8) & 7, ni = (i >> 6) & 3, l = i & 63;
    int row = o4 * 128 + wc * 64 + ni * 16 + (l & 15);
    int col = s * 32 + (l >> 4) * 8;
    U4 hh, ll;
#pragma unroll
    for (int e = 0; e < 8; ++e) split2(wsrc[(size_t)row * 256 + col + e], hh.s[e], ll.s[e]);
    *reinterpret_cast<uint4*>(&ph[(size_t)i * 8]) = hh.v;
    *reinterpret_cast<uint4*>(&pl[(size_t)i * 8]) = ll.v;
}

// ---------------------------------------------------------------- proxy-side K/V (tiny, fp32 VALU)
struct KVArgs {
    const float *proxy;
    const float *ow1, *og1, *ob1, *om1, *ov1;
    const float *ow2, *og2, *ob2, *om2, *ov2;
    const float *dw,  *dg,  *db,  *dm,  *dv;
    float *kmat;   // [B][256][19]
    float *vmat;   // [B][19][256]
};
__global__ __launch_bounds__(256) void kv_kernel(KVArgs a) {
    __shared__ float pl[512 * 19];
    __shared__ float t1[256 * 19];
    const int t = threadIdx.x;
    const int b = blockIdx.x;
    const float* pb = a.proxy + (size_t)b * 512 * 19;
    for (int i = t; i < 512 * 19; i += 256) pl[i] = pb[i];
    __syncthreads();
    const int o = t;
    {
        float acc[19] = {0.f};
        const float* wr = a.ow1 + (size_t)o * 512;
        for (int c = 0; c < 512; ++c) {
            float wv = wr[c];
#pragma unroll
            for (int kk = 0; kk < 19; ++kk) acc[kk] += wv * pl[c * 19 + kk];
        }
        float sc = a.og1[o] * __frsqrt_rn(a.ov1[o] + 1e-5f);
        float sh = a.ob1[o] - a.om1[o] * sc;
#pragma unroll
        for (int kk = 0; kk < 19; ++kk) t1[o * 19 + kk] = fmaxf(acc[kk] * sc + sh, 0.f);
    }
    __syncthreads();
    {
        float acc[19] = {0.f};
        const float* wr = a.ow2 + (size_t)o * 256;
        for (int c = 0; c < 256; ++c) {
            float wv = wr[c];
#pragma unroll
            for (int kk = 0; kk < 19; ++kk) acc[kk] += wv * t1[c * 19 + kk];
        }
        float sc = a.og2[o] * __frsqrt_rn(a.ov2[o] + 1e-5f);
        float sh = a.ob2[o] - a.om2[o] * sc;
#pragma unroll
        for (int kk = 0; kk < 19; ++kk)
            a.kmat[((size_t)b * 256 + o) * 19 + kk] = fmaxf(acc[kk] * sc + sh, 0.f);
    }
    {
        float acc[19] = {0.f};
        const float* wr = a.dw + (size_t)o * 512;
        for (int c = 0; c < 512; ++c) {
            float wv = wr[c];
#pragma unroll
            for (int kk = 0; kk < 19; ++kk) acc[kk] += wv * pl[c * 19 + kk];
        }
        float sc = a.dg[o] * __frsqrt_rn(a.dv[o] + 1e-5f);
        float sh = a.db[o] - a.dm[o] * sc;
#pragma unroll
        for (int kk = 0; kk < 19; ++kk)
            a.vmat[((size_t)b * 19 + kk) * 256 + o] = fmaxf(acc[kk] * sc + sh, 0.f);
    }
}

// ---------------------------------------------------------------- attention: 128 px/block, 8 sub-tiles of 16 px
// K/V loaded ONCE per block (8x amortization vs R18); q2 staged coalescedly per sub-tile.
// 16 threads/px; shfl_xor(16,32) + sp[4][16][19] reduction; fragment-order ctx stores.
struct AttnArgs { const float* q2f; const float* kmat; const float* vmat;
                  u16* ctxh; u16* ctxl; long long p_off; };
__global__ __launch_bounds__(256, 2) void attn_kernel(AttnArgs a) {
    __shared__ float qs[16 * 261];    // 16704 B (per sub-tile)
    __shared__ float kl[4864];        // [c][19]
    __shared__ float vl[4864];        // [kk][256]
    __shared__ float sp[4 * 16 * 19]; // wave partials
    const int t = threadIdx.x;
    const int px = t & 15, cg = t >> 4;                // cg 0..15
    const int w = t >> 6, l = t & 63;
    const size_t pl0 = (size_t)blockIdx.x * 128;       // pass-local pixel base
    const size_t gpx0 = (size_t)a.p_off + pl0;         // global pixel base (mult of 128)
    const int b = (int)(gpx0 >> 14);
    for (int i = t; i < 4864; i += 256) { kl[i] = a.kmat[(size_t)b * 4864 + i];
                                          vl[i] = a.vmat[(size_t)b * 4864 + i]; }

#pragma unroll 1
    for (int st = 0; st < 8; ++st) {
        __syncthreads();                               // prior qs/sp readers done (iter 0: no-op)
        // stage 16-px q2 sub-tile coalescedly: 1024 float4
        {
            const float* src = a.q2f + (pl0 + st * 16) * 256;
#pragma unroll
            for (int j = 0; j < 4; ++j) {
                int f = j * 256 + t;
                float4 v = reinterpret_cast<const float4*>(src)[f];
                int pr = f >> 6, col = (f & 63) * 4;
                *reinterpret_cast<float4*>(&qs[pr * 261 + col]) = v;
            }
        }
        __syncthreads();                               // qs (and iter-0 K/V) visible
        // partial sims over this thread's 16 channels
        float sim[19];
#pragma unroll
        for (int kk = 0; kk < 19; ++kk) sim[kk] = 0.f;
#pragma unroll 4
        for (int i = 0; i < 16; ++i) {
            int c = cg * 16 + i;
            float qv = qs[px * 261 + c];
#pragma unroll
            for (int kk = 0; kk < 19; ++kk) sim[kk] += qv * kl[c * 19 + kk];
        }
#pragma unroll
        for (int kk = 0; kk < 19; ++kk) {
            sim[kk] += __shfl_xor(sim[kk], 16);
            sim[kk] += __shfl_xor(sim[kk], 32);
        }
        if ((l >> 4) == 0) {
#pragma unroll
            for (int kk = 0; kk < 19; ++kk) sp[w * 304 + px * 19 + kk] = sim[kk];
        }
        __syncthreads();                               // sp visible
        // combine waves + softmax (redundant per thread; broadcast reads)
        float wgt[19];
        float mx = -1e30f;
#pragma unroll
        for (int kk = 0; kk < 19; ++kk) {
            float s0 = sp[px * 19 + kk] + sp[304 + px * 19 + kk]
                     + sp[608 + px * 19 + kk] + sp[912 + px * 19 + kk];
            wgt[kk] = s0 * 0.0625f;
            mx = fmaxf(mx, wgt[kk]);
        }
        float ssum = 0.f;
#pragma unroll
        for (int kk = 0; kk < 19; ++kk) { wgt[kk] = __expf(wgt[kk] - mx); ssum += wgt[kk]; }
        const float inv = 1.f / ssum;
#pragma unroll
        for (int kk = 0; kk < 19; ++kk) wgt[kk] *= inv;
        // ctx for this thread's 16 channels -> fragment-order stores
        const int Pg = (int)gpx0 + st * 16 + px;
        const int tile = Pg >> 6;
        const int pgg = (Pg >> 4) & 3;
        u16* th = a.ctxh + (size_t)tile * 16384;
        u16* tl = a.ctxl + (size_t)tile * 16384;
#pragma unroll
        for (int jj = 0; jj < 2; ++jj) {
            const int j = cg * 2 + jj;                 // channel octet
            const int s = j >> 2, l4c = j & 3;
            U4 hh, ll;
#pragma unroll
            for (int e = 0; e < 8; ++e) {
                int c = j * 8 + e;
                float acc = 0.f;
#pragma unroll
                for (int kk = 0; kk < 19; ++kk) acc += wgt[kk] * vl[kk * 256 + c];
                split2(acc, hh.s[e], ll.s[e]);
            }
            const int off = (s * 4 + pgg) * 512 + (l4c * 16 + px) * 8;
            *reinterpret_cast<uint4*>(&th[off]) = hh.v;
            *reinterpret_cast<uint4*>(&tl[off]) = ll.v;
        }
    }
}

// ---------------------------------------------------------------- FUSED gemm1+gemm2, 128-px blocks, 2 blocks/CU (R18)
struct F12Args {
    const float* Xf;
    const u16 *W1h, *W1l, *W2h, *W2l;   // packed
    const float *g1, *b1, *m1, *v1;
    const float *g2, *b2, *m2, *v2;
    float* q2f;     // [px][256] fp32
    int m_off;
};
__global__ __launch_bounds__(256, 2) void fused12_kernel(F12Args a) {
    __shared__ char LB[81920];
    u16* xs = (u16*)LB;               // phase1: 2 planes x [128][32] u16 (16384 B, single buf)
    u16* wb = (u16*)(LB + 16384);     // phase1: 2 buf x 2 planes x [256][32] u16 (65536 B)
    u16* q1 = (u16*)LB;               // phase2: 2 planes x [32][280] u16 (35840 B)
    float* tf = (float*)LB;           // phase2 epilogue: [32][260] f32 (33280 B), aliases q1

    const int t = threadIdx.x;
    const int l = t & 63, w = t >> 6;
    const int wr = w >> 1, wc = w & 1;
    const int l15 = l & 15, l4 = l >> 4;
    const int mloc = blockIdx.x * 128;
    const int mg = a.m_off + mloc;
    const int bb = mg >> 14, nb = mg & 16383;   // 128 | 16384 -> no batch straddle

    f32x4 acc1[4][8];
#pragma unroll
    for (int mi = 0; mi < 4; ++mi)
#pragma unroll
        for (int ni = 0; ni < 8; ++ni) acc1[mi][ni] = f32x4{0.f, 0.f, 0.f, 0.f};

    float fxA[8], fxB[8];             // two tasks: px = t&127, octs {t>>7, 2+(t>>7)}

    auto loadX = [&](int s) {
        const int px = t & 127, oa = t >> 7;
        const float* s0 = a.Xf + (((size_t)bb * 512 + s * 32 + oa * 8) << 14) + nb + px;
        const float* s1 = a.Xf + (((size_t)bb * 512 + s * 32 + (oa + 2) * 8) << 14) + nb + px;
#pragma unroll
        for (int e = 0; e < 8; ++e) { fxA[e] = s0[(size_t)e << 14]; fxB[e] = s1[(size_t)e << 14]; }
    };
    auto writeX = [&]() {
        const int px = t & 127, oa = t >> 7;
        U4 phA, plA, phB, plB;
#pragma unroll
        for (int e = 0; e < 8; ++e) { split2(fxA[e], phA.s[e], plA.s[e]);
                                      split2(fxB[e], phB.s[e], plB.s[e]); }
        int posA = px * 32 + ((oa ^ swz(px)) * 8);
        int posB = px * 32 + (((oa + 2) ^ swz(px)) * 8);
        *reinterpret_cast<uint4*>(&xs[posA]) = phA.v;
        *reinterpret_cast<uint4*>(&xs[4096 + posA]) = plA.v;
        *reinterpret_cast<uint4*>(&xs[posB]) = phB.v;
        *reinterpret_cast<uint4*>(&xs[4096 + posB]) = plB.v;
    };
    auto dmaW1 = [&](int s, int buf) {
        const u16* bh = a.W1h + (size_t)s * 8192 + l * 8;
        const u16* bl2 = a.W1l + (size_t)s * 8192 + l * 8;
#pragma unroll
        for (int g = 0; g < 4; ++g) {
            const int rg = w * 4 + g;
            gload16(bh + rg * 512, &wb[buf * 16384 + rg * 512]);
            gload16(bl2 + rg * 512, &wb[buf * 16384 + 8192 + rg * 512]);
        }
    };

    // ---------------- phase 1: K=512 in 16 steps of 32
    loadX(0); dmaW1(0, 0);
    writeX();
    __syncthreads();                             // xs(0) + wb(0) ready
    int cur = 0;
    for (int s = 0; s < 16; ++s) {
        if (s < 15) dmaW1(s + 1, cur ^ 1);       // covered by MFMA below
        bf16x8 ah[4], am[4];
#pragma unroll
        for (int mi = 0; mi < 4; ++mi) {
            int ar = wr * 64 + mi * 16 + l15;
            int ap = ar * 32 + ((l4 ^ swz(ar)) * 8);
            ah[mi] = *reinterpret_cast<const bf16x8*>(&xs[ap]);
            am[mi] = *reinterpret_cast<const bf16x8*>(&xs[4096 + ap]);
        }
#pragma unroll
        for (int ni = 0; ni < 8; ++ni) {
            int br = wc * 128 + ni * 16 + l15;
            int bp = cur * 16384 + br * 32 + ((l4 ^ swz(br)) * 8);
            bf16x8 bh = *reinterpret_cast<const bf16x8*>(&wb[bp]);
            bf16x8 bl_ = *reinterpret_cast<const bf16x8*>(&wb[8192 + bp]);
#pragma unroll
            for (int mi = 0; mi < 4; ++mi) {
                acc1[mi][ni] = __builtin_amdgcn_mfma_f32_16x16x32_bf16(ah[mi], bh, acc1[mi][ni], 0, 0, 0);
                acc1[mi][ni] = __builtin_amdgcn_mfma_f32_16x16x32_bf16(ah[mi], bl_, acc1[mi][ni], 0, 0, 0);
                acc1[mi][ni] = __builtin_amdgcn_mfma_f32_16x16x32_bf16(am[mi], bh, acc1[mi][ni], 0, 0, 0);
            }
        }
        __syncthreads();                         // barA: xs reads done, dma(s+1) drained
        if (s < 15) {
            loadX(s + 1);                        // issue x loads (other block covers window)
            writeX();                            // overwrite single xs
            __syncthreads();                     // barB: xs(s+1) visible
        }
        cur ^= 1;
    }

    // BN coefficients
    float scl1[8], shf1[8];
#pragma unroll
    for (int ni = 0; ni < 8; ++ni) {
        int o = wc * 128 + ni * 16 + l15;
        scl1[ni] = a.g1[o] * __frsqrt_rn(a.v1[o] + 1e-5f);
        shf1[ni] = a.b1[o] - a.m1[o] * scl1[ni];
    }
    float scl2[4], shf2[4];
#pragma unroll
    for (int ni = 0; ni < 4; ++ni) {
        int o = w * 64 + ni * 16 + l15;
        scl2[ni] = a.g2[o] * __frsqrt_rn(a.v2[o] + 1e-5f);
        shf2[ni] = a.b2[o] - a.m2[o] * scl2[ni];
    }

    // ---------------- phase 2: 4 chunk-pairs of 32 px
#pragma unroll
    for (int cp = 0; cp < 4; ++cp) {
        __syncthreads();
#pragma unroll
        for (int ni = 0; ni < 8; ++ni) {
            int o1 = wc * 128 + ni * 16 + l15;
#pragma unroll
            for (int r = 0; r < 4; ++r) {
                int row = wr * 16 + l4 * 4 + r;
                float y = fmaxf(acc1[cp][ni][r] * scl1[ni] + shf1[ni], 0.f);
                u16 h, lo; split2(y, h, lo);
                int pos = row * 280 + o1;
                q1[pos] = h;
                q1[8960 + pos] = lo;
            }
        }
        __syncthreads();

        f32x4 acc2[2][4];
#pragma unroll
        for (int m = 0; m < 2; ++m)
#pragma unroll
            for (int ni = 0; ni < 4; ++ni) acc2[m][ni] = f32x4{0.f, 0.f, 0.f, 0.f};

#pragma unroll
        for (int s2 = 0; s2 < 8; ++s2) {
            bf16x8 a2h[2], a2m[2];
#pragma unroll
            for (int m = 0; m < 2; ++m) {
                int ap = (m * 16 + l15) * 280 + (s2 * 4 + l4) * 8;
                a2h[m] = *reinterpret_cast<const bf16x8*>(&q1[ap]);
                a2m[m] = *reinterpret_cast<const bf16x8*>(&q1[8960 + ap]);
            }
            const size_t bo0 = (size_t)(w * 8 + s2) * 2048 + l * 8;
#pragma unroll
            for (int ni = 0; ni < 4; ++ni) {
                bf16x8 b2h = *reinterpret_cast<const bf16x8*>(&a.W2h[bo0 + ni * 512]);
                bf16x8 b2l = *reinterpret_cast<const bf16x8*>(&a.W2l[bo0 + ni * 512]);
#pragma unroll
                for (int m = 0; m < 2; ++m) {
                    acc2[m][ni] = __builtin_amdgcn_mfma_f32_16x16x32_bf16(a2h[m], b2h, acc2[m][ni], 0, 0, 0);
                    acc2[m][ni] = __builtin_amdgcn_mfma_f32_16x16x32_bf16(a2h[m], b2l, acc2[m][ni], 0, 0, 0);
                    acc2[m][ni] = __builtin_amdgcn_mfma_f32_16x16x32_bf16(a2m[m], b2h, acc2[m][ni], 0, 0, 0);
                }
            }
        }
        __syncthreads();

#pragma unroll
        for (int m = 0; m < 2; ++m)
#pragma unroll
            for (int ni = 0; ni < 4; ++ni) {
                int o2 = w * 64 + ni * 16 + l15;
#pragma unroll
                for (int r = 0; r < 4; ++r) {
                    int row = m * 16 + l4 * 4 + r;
                    tf[row * 260 + o2] = fmaxf(acc2[m][ni][r] * scl2[ni] + shf2[ni], 0.f);
                }
            }
        __syncthreads();
#pragma unroll
        for (int j = 0; j < 8; ++j) {
            int task = j * 256 + t;
            int row = task >> 6, c4 = task & 63;
            int gpx = mloc + (row >> 4) * 64 + cp * 16 + (row & 15);
            *reinterpret_cast<float4*>(&a.q2f[(size_t)gpx * 256 + c4 * 4]) =
                *reinterpret_cast<const float4*>(&tf[row * 260 + c4 * 4]);
        }
    }
}

// ---------------------------------------------------------------- gemm_up: packed ctx + packed uw -> out (unchanged)
struct GUArgs {
    const u16 *Ah, *Al, *Wh, *Wl;     // packed
    const float *gg, *bbv, *mmv, *vvv;
    float* Yf;
};
__global__ __launch_bounds__(256, 4) void gemm_up_kernel(GUArgs a) {
    __shared__ float ldsf[128 * 68];          // epilogue only (34816 B)
    const int t = threadIdx.x;
    const int l = t & 63;
    const int w = t >> 6;
    const int wr = w >> 1, wc = w & 1;
    const int l15 = l & 15, l4 = l >> 4;
    const int id = blockIdx.y * 4 + blockIdx.x;
    const int wid = (id & 7) * 1024 + (id >> 3);  // bijective XCD chunking (nwg=8192)
    const int o0 = (wid & 3) * 128;
    const int m  = (wid >> 2) * 64;
    const int bb = m >> 14;
    const int nb = m & 16383;

    f32x4 acc[2][4];
#pragma unroll
    for (int mi = 0; mi < 2; ++mi)
#pragma unroll
        for (int ni = 0; ni < 4; ++ni) acc[mi][ni] = f32x4{0.f, 0.f, 0.f, 0.f};

    const size_t aoff0 = (size_t)(wid >> 2) * 16384 + (size_t)(wr * 2) * 512 + l * 8;
    const size_t woff0 = (size_t)(((wid & 3) * 2 + wc) * 8) * 2048 + l * 8;

#pragma unroll 2
    for (int s = 0; s < 8; ++s) {             // barrier-free
        const size_t as = aoff0 + (size_t)s * 2048;
        const size_t wso = woff0 + (size_t)s * 2048;
        bf16x8 ah[2], al[2], bh[4], bl[4];
#pragma unroll
        for (int mi = 0; mi < 2; ++mi) {
            ah[mi] = *reinterpret_cast<const bf16x8*>(a.Ah + as + mi * 512);
            al[mi] = *reinterpret_cast<const bf16x8*>(a.Al + as + mi * 512);
        }
#pragma unroll
        for (int ni = 0; ni < 4; ++ni) {
            bh[ni] = *reinterpret_cast<const bf16x8*>(a.Wh + wso + ni * 512);
            bl[ni] = *reinterpret_cast<const bf16x8*>(a.Wl + wso + ni * 512);
        }
#pragma unroll
        for (int mi = 0; mi < 2; ++mi)
#pragma unroll
            for (int ni = 0; ni < 4; ++ni) {
                acc[mi][ni] = __builtin_amdgcn_mfma_f32_16x16x32_bf16(ah[mi], bh[ni], acc[mi][ni], 0, 0, 0);
                acc[mi][ni] = __builtin_amdgcn_mfma_f32_16x16x32_bf16(ah[mi], bl[ni], acc[mi][ni], 0, 0, 0);
                acc[mi][ni] = __builtin_amdgcn_mfma_f32_16x16x32_bf16(al[mi], bh[ni], acc[mi][ni], 0, 0, 0);
            }
    }

    float scl[4], shf[4];
#pragma unroll
    for (int ni = 0; ni < 4; ++ni) {
        int o = o0 + wc * 64 + ni * 16 + l15;
        scl[ni] = a.gg[o] * __frsqrt_rn(a.vvv[o] + 1e-5f);
        shf[ni] = a.bbv[o] - a.mmv[o] * scl[ni];
    }

#pragma unroll
    for (int ni = 0; ni < 4; ++ni) {
        int o_l = wc * 64 + ni * 16 + l15;
#pragma unroll
        for (int mi = 0; mi < 2; ++mi)
#pragma unroll
            for (int r = 0; r < 4; ++r) {
                int n_l = wr * 32 + mi * 16 + l4 * 4 + r;
                float y = fmaxf(acc[mi][ni][r] * scl[ni] + shf[ni], 0.f);
                ldsf[o_l * 68 + n_l] = y;
            }
    }
    __syncthreads();
#pragma unroll
    for (int j = 0; j < 8; ++j) {
        int idx = j * 256 + t;
        int row = idx >> 4, c4 = (idx & 15) * 4;
        *reinterpret_cast<float4*>(&a.Yf[((size_t)bb << 23) + (size_t)(o0 + row) * 16384 + nb + c4]) =
            *reinterpret_cast<const float4*>(&ldsf[row * 68 + c4]);
    }
}

// ---------------------------------------------------------------- launch
extern "C" void kernel_launch(void* const* d_in, const int* in_sizes, int n_in,
                              void* d_out, int out_size, void* d_ws, size_t ws_size,
                              hipStream_t stream) {
    const float* x     = (const float*)d_in[0];
    const float* proxy = (const float*)d_in[1];
    const float* pw1 = (const float*)d_in[2];
    const float* pg1 = (const float*)d_in[3];
    const float* pb1 = (const float*)d_in[4];
    const float* pm1 = (const float*)d_in[5];
    const float* pv1 = (const float*)d_in[6];
    const float* pw2 = (const float*)d_in[7];
    const float* pg2 = (const float*)d_in[8];
    const float* pb2 = (const float*)d_in[9];
    const float* pm2 = (const float*)d_in[10];
    const float* pv2 = (const float*)d_in[11];
    const float* ow1 = (const float*)d_in[12];
    const float* og1 = (const float*)d_in[13];
    const float* ob1 = (const float*)d_in[14];
    const float* om1 = (const float*)d_in[15];
    const float* ov1 = (const float*)d_in[16];
    const float* ow2 = (const float*)d_in[17];
    const float* og2 = (const float*)d_in[18];
    const float* ob2 = (const float*)d_in[19];
    const float* om2 = (const float*)d_in[20];
    const float* ov2 = (const float*)d_in[21];
    const float* dw  = (const float*)d_in[22];
    const float* dg  = (const float*)d_in[23];
    const float* db  = (const float*)d_in[24];
    const float* dm  = (const float*)d_in[25];
    const float* dv  = (const float*)d_in[26];
    const float* uw  = (const float*)d_in[27];
    const float* ug  = (const float*)d_in[28];
    const float* ub  = (const float*)d_in[29];
    const float* um  = (const float*)d_in[30];
    const float* uv  = (const float*)d_in[31];

    char* ws = (char*)d_ws;
    u16* w1ph = (u16*)(ws + 0);                  // 262144 B (packed)
    u16* w1pl = (u16*)(ws + 262144);
    u16* w2ph = (u16*)(ws + 524288);             // 131072 B (packed)
    u16* w2pl = (u16*)(ws + 655360);
    u16* wuph = (u16*)(ws + 786432);             // 262144 B (packed)
    u16* wupl = (u16*)(ws + 1048576);
    float* kmat = (float*)(ws + 1310720);        // 155648 B
    float* vmat = (float*)(ws + 1466368);        // 155648 B -> ends 1622016
    u16* ctxh = (u16*)(ws + 2097152);            // 67108864 B (fragment-order)
    u16* ctxl = (u16*)(ws + 69206016);           // 67108864 B -> ends 136314880
    float* q2f = (float*)(ws + 136314880ull);    // 134217728 B, [px][256] fp32

    pack_w1_kernel<<<64, 256, 0, stream>>>(pw1, w1ph, w1pl);
    pack_w2_kernel<<<32, 256, 0, stream>>>(pw2, w2ph, w2pl);
    pack_wu_kernel<<<64, 256, 0, stream>>>(uw,  wuph, wupl);

    KVArgs ka{proxy, ow1, og1, ob1, om1, ov1, ow2, og2, ob2, om2, ov2,
              dw, dg, db, dm, dv, kmat, vmat};
    kv_kernel<<<8, 256, 0, stream>>>(ka);

    // fused12: x -> q1 -> q2 (128-px blocks)
    F12Args fa{x, w1ph, w1pl, w2ph, w2pl,
               pg1, pb1, pm1, pv1, pg2, pb2, pm2, pv2, q2f, 0};
    fused12_kernel<<<1024, 256, 0, stream>>>(fa);

    // attention: 128 px/block, K/V amortized, coalesced q staging
    AttnArgs aa{q2f, kmat, vmat, ctxh, ctxl, 0};
    attn_kernel<<<1024, 256, 0, stream>>>(aa);

    // gemm_up: packed ctx -> out[b][o][n] fp32
    GUArgs ga{ctxh, ctxl, wuph, wupl, ug, ub, um, uv, (float*)d_out};
    gemm_up_kernel<<<dim3(4, 2048), 256, 0, stream>>>(ga);
}